// Round 11
// baseline (1441.011 us; speedup 1.0000x reference)
//
#include <hip/hip_runtime.h>

#define T_     24
#define LAMDA_ 0.2f

// output layout (flat f32): outs[24,64,256] | cs[64,256] | las[24,64,32] | gas[24,64,256]
#define OFF_CS  393216
#define OFF_LAS 409600
#define OFF_GAS 458752

#define WS_EL   409600      // ws float offset of El region (Eg: 64*6400 floats)

__device__ __forceinline__ float clamp15(float x){ return fminf(15.f, fmaxf(-15.f, x)); }
__device__ __forceinline__ float rcp_(float x){ return __builtin_amdgcn_rcpf(x); }
__device__ __forceinline__ float fma4(float4 w, float4 x, float a){
    a = fmaf(w.x, x.x, a); a = fmaf(w.y, x.y, a);
    a = fmaf(w.z, x.z, a); a = fmaf(w.w, x.w, a);
    return a;
}

// ---------------------------------------------------------------------------
// Kernel 1 (64 x 1024): t-invariant precompute.
//   Eg = exp(2*clamp(hf_g))  -> ws[b*6400 + s*25 + o]   (stride-25: LDS-conflict-free later)
//   El = exp(2*clamp(hf_l))  -> ws[WS_EL + b*800 + l*25 + o]
// ---------------------------------------------------------------------------
__global__ __launch_bounds__(1024) void init_kernel(
    const float* __restrict__ ls,  const float* __restrict__ gs,
    const float* __restrict__ Wcl, const float* __restrict__ bcl,
    const float* __restrict__ Wcg, const float* __restrict__ bcg,
    float* __restrict__ ws)
{
    __shared__ __align__(16) float wcg[6144];
    const int b = blockIdx.x, tid = threadIdx.x;
    const int s = tid & 255, ogrp = tid >> 8;

    float acc[6];
#pragma unroll
    for (int i = 0; i < 6; i++) acc[i] = bcg[ogrp*6 + i];

    for (int hc = 0; hc < 3; hc++) {
        for (int k = tid; k < 6144; k += 1024) {
            const int o = k >> 8, r = k & 255;
            wcg[k] = Wcg[o*768 + hc*256 + r];
        }
        __syncthreads();
        for (int cc = 0; cc < 8; cc++) {
            const float4* gp = (const float4*)(gs + ((size_t)b*196608 + (hc*8 + cc)*8192 + s*32));
#pragma unroll
            for (int m = 0; m < 8; m++) {
                const float4 g4 = gp[m];
#pragma unroll
                for (int i = 0; i < 6; i++) {
                    const float4 w = ((const float4*)(wcg + ((ogrp*6 + i)*256 + cc*32)))[m];
                    acc[i] = fma4(w, g4, acc[i]);
                }
            }
        }
        __syncthreads();
    }
#pragma unroll
    for (int i = 0; i < 6; i++)
        ws[b*6400 + s*25 + (ogrp*6 + i)] = __expf(2.f*clamp15(acc[i]));

    if (tid < 768) {
        const int o = tid >> 5, l = tid & 31;
        float a = bcl[o];
        for (int c = 0; c < 24; c++)
            a = fmaf(Wcl[o*24 + c], ls[b*768 + c*32 + l], a);
        ws[WS_EL + b*800 + l*25 + o] = __expf(2.f*clamp15(a));
    }
}

// ---------------------------------------------------------------------------
// Kernel 2 (64 x 64): the recurrence, ONE WAVE per batch.
// Single-wave barriers are ~free; __launch_bounds__(64,1) -> 512-VGPR budget
// (R4-R10's 16-wave/64-VGPR structure was stall/spill-bound at ~38 us/step
// invariant to all phase restructuring).
// ---------------------------------------------------------------------------
__global__ __launch_bounds__(64, 1) void step_kernel(
    const float* __restrict__ li,  const float* __restrict__ gi,
    const float* __restrict__ dist,
    const float* __restrict__ la0, const float* __restrict__ ga0,
    const float* __restrict__ Wll, const float* __restrict__ bll, const float* __restrict__ vl,
    const float* __restrict__ Wlg, const float* __restrict__ blg, const float* __restrict__ vg,
    const float* __restrict__ Wih, const float* __restrict__ bih, const float* __restrict__ bhh,
    const float* __restrict__ ws,  float* __restrict__ out)
{
    __shared__ float Eg[6400];               // [s*25+o]
    __shared__ float El[800];                // [l*25+o]
    __shared__ __align__(16) float xv[288];
    __shared__ __align__(16) float cq[256];
    __shared__ float gbuf[768];
    __shared__ float bsum[768];
    __shared__ float dstf[256];
    __shared__ __align__(8) float2 fv[48];   // 0..23: (F_l,v_l); 24..47: (F_g,v_g)
    __shared__ float slb[32];
    __shared__ float cb[2];

    const int b = blockIdx.x, ln = threadIdx.x;
    const int u8 = ln & 7, rsub = ln >> 3;

    // ---- stage t-invariants ----
    for (int k = ln; k < 6400; k += 64) Eg[k] = ws[b*6400 + k];
    for (int k = ln; k < 800;  k += 64) El[k] = ws[WS_EL + b*800 + k];
    for (int k = ln; k < 768;  k += 64) {
        const int wrow = k + ((k >= 256) ? 256 : 0);
        bsum[k] = bih[wrow] + bhh[wrow];
    }
    for (int k = ln; k < 256;  k += 64) dstf[k] = dist[b*256 + k];
    if (ln == 0) { float s1 = 0.f; for (int d = 0; d < 24; d++) s1 += vl[d]; cb[0] = s1; }
    if (ln == 1) { float s1 = 0.f; for (int d = 0; d < 24; d++) s1 += vg[d]; cb[1] = s1; }
    // x for t=0
    if (ln < 32) xv[ln] = la0[b*32 + ln] * li[b*32 + ln];
#pragma unroll
    for (int k = 0; k < 4; k++) {
        const int s2 = ln + 64*k;
        xv[32 + s2] = ga0[b*256 + s2] * gi[b*256 + s2];
    }
    __syncthreads();

    for (int t = 0; t < T_; t++) {
        // ---- A: gates GEMV. 8 lanes/row, x in regs, depth-2 W pipeline ----
        {
            float4 xr[9];
            const float4* xv4 = (const float4*)xv;
#pragma unroll
            for (int j = 0; j < 9; j++) xr[j] = xv4[j*8 + u8];

            auto LOADW = [&](int g, float4* w) {
                const int row  = g*8 + rsub;
                const int wrow = row + ((row >= 256) ? 256 : 0);
                const float4* wp = (const float4*)(Wih + wrow*288);
#pragma unroll
                for (int j = 0; j < 9; j++) w[j] = wp[j*8 + u8];
            };
            auto COMPUTE = [&](int g, const float4* w) {
                float a0 = 0.f, a1 = 0.f, a2 = 0.f;
#pragma unroll
                for (int j = 0; j < 9; j += 3) {
                    a0 = fma4(w[j],   xr[j],   a0);
                    a1 = fma4(w[j+1], xr[j+1], a1);
                    a2 = fma4(w[j+2], xr[j+2], a2);
                }
                float a = (a0 + a1) + a2;
                a += __shfl_xor(a, 1); a += __shfl_xor(a, 2); a += __shfl_xor(a, 4);
                if (u8 == 0) {
                    const int row = g*8 + rsub;
                    gbuf[row] = a + bsum[row];
                }
            };

            float4 wA[9], wB[9];
            LOADW(0, wA);
            for (int g = 0; g < 96; g += 2) {
                LOADW(g + 1, wB);
                COMPUTE(g, wA);
                if (g + 2 < 96) LOADW(g + 2, wA);
                COMPUTE(g + 1, wB);
            }
        }
        __syncthreads();

        // ---- B: c = sig(i)*tanh(g); h = sig(o)*tanh(c); 4 units/lane ----
#pragma unroll
        for (int k = 0; k < 4; k++) {
            const int u = ln + 64*k;
            const float ig = gbuf[u], gg = gbuf[256 + u], ot = gbuf[512 + u];
            const float sig_i = rcp_(1.f + __expf(-ig));
            const float th_g  = 1.f - 2.f*rcp_(1.f + __expf(2.f*clamp15(gg)));
            const float c     = sig_i * th_g;
            const float sig_o = rcp_(1.f + __expf(-ot));
            const float th_c  = 1.f - 2.f*rcp_(1.f + __expf(2.f*c));
            cq[u] = c;
            out[t*16384 + b*256 + u] = sig_o * th_c;
            if (t == T_ - 1) out[OFF_CS + b*256 + u] = c;
        }
        __syncthreads();

        // ---- C: 48 dots, one lane each (cq reads broadcast) ----
        if (ln < 48) {
            const float* Wr = (ln < 24) ? (Wll + ln*256) : (Wlg + (ln - 24)*256);
            const float4* wp = (const float4*)Wr;
            const float4* cp = (const float4*)cq;
            float a0 = 0.f, a1 = 0.f;
            for (int j = 0; j < 64; j += 2) {
                a0 = fma4(wp[j],   cp[j],   a0);
                a1 = fma4(wp[j+1], cp[j+1], a1);
            }
            const float bias = (ln < 24) ? bll[ln] : blg[ln - 24];
            const float F = __expf(2.f*clamp15(a0 + a1 + bias));
            fv[ln] = make_float2(F, (ln < 24) ? vl[ln] : vg[ln - 24]);
        }
        __syncthreads();

        // prefetch next-step inputs (regs are plentiful now)
        float liN = 0.f, gN0 = 0.f, gN1 = 0.f, gN2 = 0.f, gN3 = 0.f;
        if (t < T_ - 1) {
            if (ln < 32) liN = li[(t+1)*2048 + b*32 + ln];
            gN0 = gi[(t+1)*16384 + b*256 + ln];
            gN1 = gi[(t+1)*16384 + b*256 + ln + 64];
            gN2 = gi[(t+1)*16384 + b*256 + ln + 128];
            gN3 = gi[(t+1)*16384 + b*256 + ln + 192];
        }

        // (F,v) into registers
        float Fl_[24], vl_[24], Fg_[24], vg_[24];
#pragma unroll
        for (int d = 0; d < 24; d++) {
            const float2 p = fv[d];      Fl_[d] = p.x; vl_[d] = p.y;
            const float2 q = fv[24 + d]; Fg_[d] = q.x; vg_[d] = q.y;
        }

        // ---- D-l: s_l (12 (l,o) items/lane) + softmax over 32 ----
        {
            const int l = ln >> 1, ob = (ln & 1)*12;
            float b0 = 0.f, b1 = 0.f;
            float Ec = El[l*25 + ob];
            for (int oo = 0; oo < 12; oo++) {
                const float En = (oo < 11) ? El[l*25 + ob + oo + 1] : 0.f;
#pragma unroll
                for (int d = 0; d < 24; d += 2) {
                    b0 = fmaf(vl_[d],   rcp_(fmaf(Ec, Fl_[d],   1.f)), b0);
                    b1 = fmaf(vl_[d+1], rcp_(fmaf(Ec, Fl_[d+1], 1.f)), b1);
                }
                Ec = En;
            }
            float tot = b0 + b1;
            tot += __shfl_xor(tot, 1);           // both lanes of pair hold full sum
            const float sv = 24.f*cb[0] - 2.f*tot;
            float m = sv;
#pragma unroll
            for (int mk = 2; mk <= 32; mk <<= 1) m = fmaxf(m, __shfl_xor(m, mk));
            const float e = __expf(sv - m);
            float ss = e;
#pragma unroll
            for (int mk = 2; mk <= 32; mk <<= 1) ss += __shfl_xor(ss, mk);
            const float rl = e * rcp_(ss);
            if ((ln & 1) == 0) {
                out[OFF_LAS + t*2048 + b*32 + l] = rl;
                slb[l] = rl;
            }
        }
        __syncthreads();

        // ---- D-g: s_g (4 s/lane, 24 o each) + softmax over 256 + x-build ----
        {
            float vv[4];
#pragma unroll
            for (int k = 0; k < 4; k++) {
                const int s2 = ln + 64*k;
                float a0 = 0.f, a1 = 0.f;
                float Ec = Eg[s2*25];
                for (int o = 0; o < 24; o++) {
                    const float En = (o < 23) ? Eg[s2*25 + o + 1] : 0.f;
#pragma unroll
                    for (int d = 0; d < 24; d += 2) {
                        a0 = fmaf(vg_[d],   rcp_(fmaf(Ec, Fg_[d],   1.f)), a0);
                        a1 = fmaf(vg_[d+1], rcp_(fmaf(Ec, Fg_[d+1], 1.f)), a1);
                    }
                    Ec = En;
                }
                vv[k] = (1.f - LAMDA_)*(24.f*cb[1] - 2.f*(a0 + a1)) + LAMDA_*dstf[s2];
            }
            float m = fmaxf(fmaxf(vv[0], vv[1]), fmaxf(vv[2], vv[3]));
#pragma unroll
            for (int mk = 1; mk <= 32; mk <<= 1) m = fmaxf(m, __shfl_xor(m, mk));
            float ev[4]; float ss = 0.f;
#pragma unroll
            for (int k = 0; k < 4; k++) { ev[k] = __expf(vv[k] - m); ss += ev[k]; }
#pragma unroll
            for (int mk = 1; mk <= 32; mk <<= 1) ss += __shfl_xor(ss, mk);
            const float inv = rcp_(ss);
            float* og = out + OFF_GAS + t*16384 + b*256;
            const float r0 = ev[0]*inv, r1 = ev[1]*inv, r2 = ev[2]*inv, r3 = ev[3]*inv;
            og[ln] = r0; og[ln+64] = r1; og[ln+128] = r2; og[ln+192] = r3;
            if (t < T_ - 1) {
                xv[32 + ln]       = r0 * gN0;
                xv[32 + ln + 64]  = r1 * gN1;
                xv[32 + ln + 128] = r2 * gN2;
                xv[32 + ln + 192] = r3 * gN3;
                if (ln < 32) xv[ln] = slb[ln] * liN;
            }
        }
        __syncthreads();
    }
}

extern "C" void kernel_launch(void* const* d_in, const int* in_sizes, int n_in,
                              void* d_out, int out_size, void* d_ws, size_t ws_size,
                              hipStream_t stream)
{
    const float* li   = (const float*)d_in[0];
    const float* gi   = (const float*)d_in[1];
    const float* ls   = (const float*)d_in[2];
    const float* gs   = (const float*)d_in[3];
    const float* dist = (const float*)d_in[4];
    const float* la0  = (const float*)d_in[5];
    const float* ga0  = (const float*)d_in[6];
    const float* Wcl  = (const float*)d_in[7];
    const float* bcl  = (const float*)d_in[8];
    const float* Wll  = (const float*)d_in[9];
    const float* bll  = (const float*)d_in[10];
    const float* vl   = (const float*)d_in[11];
    const float* Wcg  = (const float*)d_in[12];
    const float* bcg  = (const float*)d_in[13];
    const float* Wlg  = (const float*)d_in[14];
    const float* blg  = (const float*)d_in[15];
    const float* vg   = (const float*)d_in[16];
    const float* Wih  = (const float*)d_in[17];
    const float* bih  = (const float*)d_in[18];
    const float* bhh  = (const float*)d_in[19];

    float* ws = (float*)d_ws;    // needs 460800 floats = 1.84 MB

    init_kernel<<<64, 1024, 0, stream>>>(ls, gs, Wcl, bcl, Wcg, bcg, ws);
    step_kernel<<<64, 64, 0, stream>>>(li, gi, dist, la0, ga0,
                                       Wll, bll, vl, Wlg, blg, vg,
                                       Wih, bih, bhh, ws, (float*)d_out);
}